// Round 2
// baseline (406.709 us; speedup 1.0000x reference)
//
#include <hip/hip_runtime.h>
#include <hip/hip_bf16.h>
#include <stdint.h>

#define OUT_DIM 8192
#define IN_DIM  8192
#define GS      128
#define MROWS   32
#define NSPLIT  8          // split-K chunks of 1024
#define PART_ELEMS (MROWS * OUT_DIM)

typedef __attribute__((ext_vector_type(8))) short bf16x8;   // MFMA A/B frag (4 VGPR)
typedef __attribute__((ext_vector_type(4))) float f32x4;    // MFMA C/D frag
typedef __attribute__((ext_vector_type(8))) unsigned short u16x8;

__device__ __forceinline__ unsigned short f2bf_rne(float f) {
    uint32_t v = __builtin_bit_cast(uint32_t, f);
    v += 0x7FFFu + ((v >> 16) & 1u);
    return (unsigned short)(v >> 16);
}

// x (32x8192 fp32) -> bf16 workspace. 262144 elems, 8/thread, 128 blocks.
__global__ __launch_bounds__(256) void prep_xbf(const float* __restrict__ x,
                                                unsigned short* __restrict__ xbf) {
    int i = (blockIdx.x * 256 + threadIdx.x) * 8;
    float4 a = *(const float4*)(x + i);
    float4 b = *(const float4*)(x + i + 4);
    float f[8] = {a.x, a.y, a.z, a.w, b.x, b.y, b.z, b.w};
    u16x8 u;
#pragma unroll
    for (int j = 0; j < 8; ++j) u[j] = f2bf_rne(f[j]);
    *(u16x8*)(xbf + i) = u;
}

// part[kc][t][o] = sum_{k in chunk kc} x[t][k] * ternary[o][k] * scale[o*64 + k/128]
// Wave: 16 o-cols x 32 t-rows (two 16x16x32 bf16 MFMA accs), K-chunk 1024.
__global__ __launch_bounds__(256, 4) void ternary_gemm(
    const int* __restrict__ tern, const float* __restrict__ scales,
    const unsigned short* __restrict__ xbf, float* __restrict__ part) {
    const int wave  = blockIdx.x * 4 + (threadIdx.x >> 6);
    const int lane  = threadIdx.x & 63;
    const int kc    = wave >> 9;     // 0..7   split-K chunk
    const int ntile = wave & 511;    // 0..511 o-tile
    const int n     = lane & 15;
    const int quad  = lane >> 4;
    const int o      = (ntile << 4) + n;
    const int k0base = kc << 10;

    const int* __restrict__ wrow = tern + (size_t)o * IN_DIM;
    const unsigned short* __restrict__ xr0 = xbf + n * IN_DIM;         // x row n
    const unsigned short* __restrict__ xr1 = xbf + (16 + n) * IN_DIM;  // x row 16+n

    // 8 group scales for this (o, kc) are contiguous; software-pipeline a
    // scalar load one full iteration ahead so it never serializes the body.
    const float* __restrict__ sp = scales + o * (IN_DIM / GS) + (kc << 3);
    float s_cur = sp[0];

    f32x4 acc0 = {0.f, 0.f, 0.f, 0.f};
    f32x4 acc1 = {0.f, 0.f, 0.f, 0.f};

    for (int it = 0; it < 8; ++it) {
        const unsigned int p = f2bf_rne(s_cur);          // +bf16(s), sign injected below
        float s_nxt = sp[(it < 7) ? (it + 1) : 7];       // prefetch (clamped, L1-hot)
        const int k0 = k0base + (it << 7);               // 128-aligned -> one scale group
#pragma unroll
        for (int st = 0; st < 4; ++st) {
            const int k = k0 + (st << 5) + (quad << 3);  // lane's 8 consecutive k
            int4 w0 = *(const int4*)(wrow + k);
            int4 w1 = *(const int4*)(wrow + k + 4);
            bf16x8 a0 = *(const bf16x8*)(xr0 + k);
            bf16x8 a1 = *(const bf16x8*)(xr1 + k);
            int tw[8] = {w0.x, w0.y, w0.z, w0.w, w1.x, w1.y, w1.z, w1.w};
            bf16x8 bfr;
#pragma unroll
            for (int j = 0; j < 8; ++j) {
                int t = tw[j];
                // t in {-1,0,1}: (t & 0x8000) is the sign bit for t==-1, 0 otherwise.
                unsigned int v = p | ((unsigned int)t & 0x8000u);
                bfr[j] = (short)((t == 0) ? 0u : v);
            }
            acc0 = __builtin_amdgcn_mfma_f32_16x16x32_bf16(a0, bfr, acc0, 0, 0, 0);
            acc1 = __builtin_amdgcn_mfma_f32_16x16x32_bf16(a1, bfr, acc1, 0, 0, 0);
        }
        s_cur = s_nxt;
    }

    // D layout: col = lane&15 (=o), row t = quad*4 + reg. Plain stores, no atomics.
    float* __restrict__ prow = part + (size_t)kc * PART_ELEMS;
#pragma unroll
    for (int r = 0; r < 4; ++r) {
        prow[(quad * 4 + r) * OUT_DIM + o]        = acc0[r];
        prow[(quad * 4 + r + 16) * OUT_DIM + o]   = acc1[r];
    }
}

// out = sum over 8 split-K partials. 256 blocks x 256 thr x float4.
__global__ __launch_bounds__(256) void reduce_parts(const float* __restrict__ part,
                                                    float* __restrict__ out) {
    const int i = (blockIdx.x * 256 + threadIdx.x) * 4;
    float4 s = *(const float4*)(part + i);
#pragma unroll
    for (int kc = 1; kc < NSPLIT; ++kc) {
        float4 v = *(const float4*)(part + (size_t)kc * PART_ELEMS + i);
        s.x += v.x; s.y += v.y; s.z += v.z; s.w += v.w;
    }
    *(float4*)(out + i) = s;
}

extern "C" void kernel_launch(void* const* d_in, const int* in_sizes, int n_in,
                              void* d_out, int out_size, void* d_ws, size_t ws_size,
                              hipStream_t stream) {
    const float* x      = (const float*)d_in[0];
    const int*   tern   = (const int*)d_in[1];
    const float* scales = (const float*)d_in[2];
    float* out = (float*)d_out;

    unsigned short* xbf = (unsigned short*)d_ws;                        // 512 KB
    float* part = (float*)((char*)d_ws + (512 << 10));                  // 8 MB

    prep_xbf<<<128, 256, 0, stream>>>(x, xbf);
    ternary_gemm<<<1024, 256, 0, stream>>>(tern, scales, xbf, part);
    reduce_parts<<<256, 256, 0, stream>>>(part, out);
}

// Round 3
// 379.790 us; speedup vs baseline: 1.0709x; 1.0709x over previous
//
#include <hip/hip_runtime.h>
#include <hip/hip_bf16.h>
#include <stdint.h>

#define OUT_DIM 8192
#define IN_DIM  8192
#define GS      128
#define MROWS   32
#define NSPLIT  8          // split-K chunks of 1024
#define PART_ELEMS (MROWS * OUT_DIM)

typedef __attribute__((ext_vector_type(8))) short bf16x8;   // MFMA A/B frag (4 VGPR)
typedef __attribute__((ext_vector_type(4))) float f32x4;    // MFMA C/D frag
typedef __attribute__((ext_vector_type(8))) unsigned short u16x8;

__device__ __forceinline__ unsigned short f2bf_rne(float f) {
    uint32_t v = __builtin_bit_cast(uint32_t, f);
    v += 0x7FFFu + ((v >> 16) & 1u);
    return (unsigned short)(v >> 16);
}

// x (32x8192 fp32) -> bf16 workspace. 262144 elems, 8/thread, 128 blocks.
__global__ __launch_bounds__(256) void prep_xbf(const float* __restrict__ x,
                                                unsigned short* __restrict__ xbf) {
    int i = (blockIdx.x * 256 + threadIdx.x) * 8;
    float4 a = *(const float4*)(x + i);
    float4 b = *(const float4*)(x + i + 4);
    float f[8] = {a.x, a.y, a.z, a.w, b.x, b.y, b.z, b.w};
    u16x8 u;
#pragma unroll
    for (int j = 0; j < 8; ++j) u[j] = f2bf_rne(f[j]);
    *(u16x8*)(xbf + i) = u;
}

// part[kc][t][o] = sum_{k in chunk kc} x[t][k] * ternary[o][k] * scale[o*64 + k/128]
// Wave: 16 o-cols x 32 t-rows (two 16x16x32 bf16 MFMA accs), K-chunk 1024.
// NOTE: no min-waves clause — (256,4) capped VGPR at 128 and the unroll-4 body
// needs ~110-150 live VGPRs -> scratch spills in the hot loop (suspected 3.5x).
__global__ __launch_bounds__(256) void ternary_gemm(
    const int* __restrict__ tern, const float* __restrict__ scales,
    const unsigned short* __restrict__ xbf, float* __restrict__ part) {
    const int wave  = blockIdx.x * 4 + (threadIdx.x >> 6);
    const int lane  = threadIdx.x & 63;
    const int kc    = wave >> 9;     // 0..7   split-K chunk
    const int ntile = wave & 511;    // 0..511 o-tile
    const int n     = lane & 15;
    const int quad  = lane >> 4;
    const int o      = (ntile << 4) + n;
    const int k0base = kc << 10;

    const int* __restrict__ wrow = tern + (size_t)o * IN_DIM;
    const unsigned short* __restrict__ xr0 = xbf + n * IN_DIM;         // x row n
    const unsigned short* __restrict__ xr1 = xbf + (16 + n) * IN_DIM;  // x row 16+n

    // 8 contiguous group scales for this (o, kc); pipeline one it ahead.
    const float* __restrict__ sp = scales + o * (IN_DIM / GS) + (kc << 3);
    float s_cur = sp[0];

    f32x4 acc0 = {0.f, 0.f, 0.f, 0.f};
    f32x4 acc1 = {0.f, 0.f, 0.f, 0.f};

#pragma unroll 1   // keep outer loop rolled: full 8x unroll would blow VGPRs
    for (int it = 0; it < 8; ++it) {
        const unsigned int p = f2bf_rne(s_cur);          // +bf16(s)
        float s_nxt = sp[(it < 7) ? (it + 1) : 7];       // prefetch (L1-hot)
        const int k0 = k0base + (it << 7);               // 128-aligned -> one group
#pragma unroll
        for (int st = 0; st < 4; ++st) {
            const int k = k0 + (st << 5) + (quad << 3);  // lane's 8 consecutive k
            int4 w0 = *(const int4*)(wrow + k);
            int4 w1 = *(const int4*)(wrow + k + 4);
            bf16x8 a0 = *(const bf16x8*)(xr0 + k);
            bf16x8 a1 = *(const bf16x8*)(xr1 + k);
            int tw[8] = {w0.x, w0.y, w0.z, w0.w, w1.x, w1.y, w1.z, w1.w};
            bf16x8 bfr;
#pragma unroll
            for (int j = 0; j < 8; ++j) {
                int t = tw[j];
                // t in {-1,0,1}: (t & 0x8000) is the sign bit iff t==-1.
                unsigned int v = p | ((unsigned int)t & 0x8000u);
                bfr[j] = (short)((t == 0) ? 0u : v);
            }
            acc0 = __builtin_amdgcn_mfma_f32_16x16x32_bf16(a0, bfr, acc0, 0, 0, 0);
            acc1 = __builtin_amdgcn_mfma_f32_16x16x32_bf16(a1, bfr, acc1, 0, 0, 0);
        }
        s_cur = s_nxt;
    }

    // D layout: col = lane&15 (=o), row t = quad*4 + reg. Plain stores.
    float* __restrict__ prow = part + (size_t)kc * PART_ELEMS;
#pragma unroll
    for (int r = 0; r < 4; ++r) {
        prow[(quad * 4 + r) * OUT_DIM + o]        = acc0[r];
        prow[(quad * 4 + r + 16) * OUT_DIM + o]   = acc1[r];
    }
}

// out = sum over 8 split-K partials. 256 blocks x 256 thr x float4.
__global__ __launch_bounds__(256) void reduce_parts(const float* __restrict__ part,
                                                    float* __restrict__ out) {
    const int i = (blockIdx.x * 256 + threadIdx.x) * 4;
    float4 s = *(const float4*)(part + i);
#pragma unroll
    for (int kc = 1; kc < NSPLIT; ++kc) {
        float4 v = *(const float4*)(part + (size_t)kc * PART_ELEMS + i);
        s.x += v.x; s.y += v.y; s.z += v.z; s.w += v.w;
    }
    *(float4*)(out + i) = s;
}

extern "C" void kernel_launch(void* const* d_in, const int* in_sizes, int n_in,
                              void* d_out, int out_size, void* d_ws, size_t ws_size,
                              hipStream_t stream) {
    const float* x      = (const float*)d_in[0];
    const int*   tern   = (const int*)d_in[1];
    const float* scales = (const float*)d_in[2];
    float* out = (float*)d_out;

    unsigned short* xbf = (unsigned short*)d_ws;                        // 512 KB
    float* part = (float*)((char*)d_ws + (512 << 10));                  // 8 MB

    prep_xbf<<<128, 256, 0, stream>>>(x, xbf);
    ternary_gemm<<<1024, 256, 0, stream>>>(tern, scales, xbf, part);
    reduce_parts<<<256, 256, 0, stream>>>(part, out);
}